// Round 1
// baseline (394.517 us; speedup 1.0000x reference)
//
#include <hip/hip_runtime.h>
#include <hip/hip_bf16.h>
#include <stdint.h>

typedef __attribute__((ext_vector_type(8))) short bf16x8;
typedef __attribute__((ext_vector_type(4))) float f32x4;

__device__ __forceinline__ float b2f(unsigned short u) {
  union { unsigned u32; float f; } c; c.u32 = ((unsigned)u) << 16; return c.f;
}
__device__ __forceinline__ unsigned short f2b(float f) {
  union { float f; unsigned u; } c; c.f = f;
  unsigned u = c.u;
  return (unsigned short)((u + 0x7FFFu + ((u >> 16) & 1u)) >> 16);  // RNE
}

// ---------------- fp32 -> bf16 cast, 8 elems/thread ----------------
__global__ __launch_bounds__(256) void cast_f32_bf16(const float* __restrict__ in,
                                                     unsigned short* __restrict__ out,
                                                     int n8) {
  int i = blockIdx.x * 256 + threadIdx.x;
  if (i >= n8) return;
  const float4* p = (const float4*)in + (size_t)i * 2;
  float4 a = p[0], b = p[1];
  union { bf16x8 v; unsigned short s[8]; } o;
  o.s[0] = f2b(a.x); o.s[1] = f2b(a.y); o.s[2] = f2b(a.z); o.s[3] = f2b(a.w);
  o.s[4] = f2b(b.x); o.s[5] = f2b(b.y); o.s[6] = f2b(b.z); o.s[7] = f2b(b.w);
  ((bf16x8*)out)[i] = o.v;
}

// ---------------- bf16 GEMM, C = A * B^T (+bias) -------------------
// A: M x K row-major (bf16), B: N x K row-major (bf16).
// 128x128 tile, BK=32, 4 waves each 64x64 (4x4 of 16x16x32 mfma).
// m97 structure: global_load_lds width=16, 2 barriers per K-step.
#define GLDS16(g, l)                                                          \
  __builtin_amdgcn_global_load_lds((const __attribute__((address_space(1))) void*)(g), \
                                   (__attribute__((address_space(3))) void*)(l), 16, 0, 0)

template <typename OutT, bool BIAS>
__global__ __launch_bounds__(256) void gemm_bt(const unsigned short* __restrict__ A,
                                               const unsigned short* __restrict__ B,
                                               OutT* __restrict__ C,
                                               const float* __restrict__ bias,
                                               int M, int N, int K) {
  __shared__ unsigned short As[128 * 32];
  __shared__ unsigned short Bs[128 * 32];
  const int tid  = threadIdx.x;
  const int lane = tid & 63;
  const int wave = tid >> 6;
  const int tileM = blockIdx.y * 128;
  const int tileN = blockIdx.x * 128;

  const int m_off = (wave >> 1) * 64;  // wave grid 2x2, each wave 64x64
  const int n_off = (wave & 1) * 64;

  f32x4 acc[4][4] = {};

  // staging: 256 threads * 16B = 4KB per issue; tile is 8KB -> 2 issues each.
  const int srow = tid >> 2;       // 0..63
  const int scol = (tid & 3) * 8;  // element col
  const unsigned short* gA = A + (size_t)(tileM + srow) * K + scol;
  const unsigned short* gB = B + (size_t)(tileN + srow) * K + scol;
  unsigned short* lA = &As[tid * 8];
  unsigned short* lB = &Bs[tid * 8];

  const int lr = lane & 15;        // fragment row/col within 16
  const int lk = (lane >> 4) * 8;  // fragment k offset

  for (int k0 = 0; k0 < K; k0 += 32) {
    GLDS16(gA, lA);
    GLDS16(gA + (size_t)64 * K, lA + 2048);
    GLDS16(gB, lB);
    GLDS16(gB + (size_t)64 * K, lB + 2048);
    gA += 32; gB += 32;
    __syncthreads();  // drains vmcnt -> LDS tiles valid

    bf16x8 af[4], bfr[4];
#pragma unroll
    for (int m = 0; m < 4; ++m)
      af[m] = *(const bf16x8*)&As[(m_off + m * 16 + lr) * 32 + lk];
#pragma unroll
    for (int n = 0; n < 4; ++n)
      bfr[n] = *(const bf16x8*)&Bs[(n_off + n * 16 + lr) * 32 + lk];

#pragma unroll
    for (int m = 0; m < 4; ++m)
#pragma unroll
      for (int n = 0; n < 4; ++n)
        acc[m][n] = __builtin_amdgcn_mfma_f32_16x16x32_bf16(af[m], bfr[n], acc[m][n], 0, 0, 0);
    __syncthreads();  // all waves done reading before next stage overwrites
  }

  // C/D layout (m89-verified): col = lane&15, row = (lane>>4)*4 + j
  const int crow0 = (lane >> 4) * 4;
  const int ccol  = lane & 15;
#pragma unroll
  for (int n = 0; n < 4; ++n) {
    const int col = tileN + n_off + n * 16 + ccol;
    float bv = 0.f;
    if (BIAS) bv = bias[col];
#pragma unroll
    for (int m = 0; m < 4; ++m) {
#pragma unroll
      for (int j = 0; j < 4; ++j) {
        const int row = tileM + m_off + m * 16 + crow0 + j;
        float v = acc[m][n][j] + bv;
        if constexpr (sizeof(OutT) == 2)
          ((unsigned short*)C)[(size_t)row * N + col] = f2b(v);
        else
          ((float*)C)[(size_t)row * N + col] = v;
      }
    }
  }
}

// ---------------- per-token attention over heads --------------------
// qkv row (3072 bf16) per token; q=qkv[h*192+d], k=+64, v=+128.
// att[h][g] = dot64(q[h],k[g])/8; softmax over g; out[h][d] = sum_g p*v.
// 1 wave per token, 4 tokens per block.
__global__ __launch_bounds__(256) void attn_heads(const unsigned short* __restrict__ qkv,
                                                  unsigned short* __restrict__ attout) {
  __shared__ float sq[4][3072];
  __shared__ float sp[4][16][17];  // padded to dodge bank conflicts
  const int wave = threadIdx.x >> 6;
  const int lane = threadIdx.x & 63;
  const size_t tok = (size_t)blockIdx.x * 4 + wave;
  const unsigned short* src = qkv + tok * 3072;

  // load + convert row to fp32 LDS: 6 iters * 64 lanes * 8 elems
#pragma unroll
  for (int it = 0; it < 6; ++it) {
    int idx = (it * 64 + lane) * 8;
    bf16x8 v = *(const bf16x8*)&src[idx];
#pragma unroll
    for (int j = 0; j < 8; ++j) sq[wave][idx + j] = b2f((unsigned short)v[j]);
  }
  __syncthreads();

  // logits: lane -> h = lane>>2, g in {(lane&3)*4 .. +3}
  {
    const int h = lane >> 2;
    const int g0 = (lane & 3) * 4;
    const float* q  = &sq[wave][h * 192];
    const float* kp = &sq[wave][g0 * 192 + 64];
    float a0 = 0, a1 = 0, a2 = 0, a3 = 0;
#pragma unroll 8
    for (int d = 0; d < 64; ++d) {
      float qd = q[d];
      a0 += qd * kp[d];
      a1 += qd * kp[192 + d];
      a2 += qd * kp[384 + d];
      a3 += qd * kp[576 + d];
    }
    const float sc = 0.125f;  // 1/sqrt(64)
    a0 *= sc; a1 *= sc; a2 *= sc; a3 *= sc;
    float mx = fmaxf(fmaxf(a0, a1), fmaxf(a2, a3));
    mx = fmaxf(mx, __shfl_xor(mx, 1));
    mx = fmaxf(mx, __shfl_xor(mx, 2));
    float e0 = __expf(a0 - mx), e1 = __expf(a1 - mx);
    float e2 = __expf(a2 - mx), e3 = __expf(a3 - mx);
    float s = e0 + e1 + e2 + e3;
    s += __shfl_xor(s, 1);
    s += __shfl_xor(s, 2);
    float inv = 1.f / s;
    sp[wave][h][g0 + 0] = e0 * inv;
    sp[wave][h][g0 + 1] = e1 * inv;
    sp[wave][h][g0 + 2] = e2 * inv;
    sp[wave][h][g0 + 3] = e3 * inv;
  }
  __syncthreads();

  // PV: lane -> h = lane>>2, d block = (lane&3)*16
  {
    const int h  = lane >> 2;
    const int d0 = (lane & 3) * 16;
    float o[16];
#pragma unroll
    for (int dd = 0; dd < 16; ++dd) o[dd] = 0.f;
#pragma unroll
    for (int g = 0; g < 16; ++g) {
      float pg = sp[wave][h][g];
      const float* vg = &sq[wave][g * 192 + 128 + d0];
#pragma unroll
      for (int dd = 0; dd < 16; ++dd) o[dd] += pg * vg[dd];
    }
    union { bf16x8 v[2]; unsigned short s[16]; } ob;
#pragma unroll
    for (int dd = 0; dd < 16; ++dd) ob.s[dd] = f2b(o[dd]);
    bf16x8* dst = (bf16x8*)&attout[tok * 1024 + h * 64 + d0];
    dst[0] = ob.v[0];
    dst[1] = ob.v[1];
  }
}

// ---------------- launch ----------------
extern "C" void kernel_launch(void* const* d_in, const int* in_sizes, int n_in,
                              void* d_out, int out_size, void* d_ws, size_t ws_size,
                              hipStream_t stream) {
  const float* x    = (const float*)d_in[0];  // (4,4096,1024)
  const float* Wqkv = (const float*)d_in[1];  // (3072,1024)
  const float* Wout = (const float*)d_in[2];  // (1024,1024)
  const float* bout = (const float*)d_in[3];  // (1024,)
  float* out = (float*)d_out;                 // (4,4096,1024) fp32

  char* ws = (char*)d_ws;
  unsigned short* xb     = (unsigned short*)(ws);                     // 33.5 MB
  unsigned short* wqkvb  = (unsigned short*)(ws + 33554432);          // 6.3 MB
  unsigned short* woutb  = (unsigned short*)(ws + 39845888);          // 2.1 MB
  unsigned short* qkv    = (unsigned short*)(ws + 41943040);          // 100.7 MB
  unsigned short* attout = (unsigned short*)(ws + 142606336);         // 33.5 MB

  cast_f32_bf16<<<8192, 256, 0, stream>>>(x, xb, 2097152);
  cast_f32_bf16<<<1536, 256, 0, stream>>>(Wqkv, wqkvb, 393216);
  cast_f32_bf16<<<512, 256, 0, stream>>>(Wout, woutb, 131072);

  // qkv = x @ Wqkv^T : M=16384 N=3072 K=1024
  gemm_bt<unsigned short, false><<<dim3(24, 128), 256, 0, stream>>>(
      xb, wqkvb, qkv, nullptr, 16384, 3072, 1024);

  attn_heads<<<4096, 256, 0, stream>>>(qkv, attout);

  // out = attout @ Wout^T + bout : M=16384 N=1024 K=1024
  gemm_bt<float, true><<<dim3(8, 128), 256, 0, stream>>>(
      attout, woutb, out, bout, 16384, 1024, 1024);
}

// Round 2
// 368.382 us; speedup vs baseline: 1.0709x; 1.0709x over previous
//
#include <hip/hip_runtime.h>
#include <hip/hip_bf16.h>
#include <stdint.h>

typedef __attribute__((ext_vector_type(8))) short bf16x8;
typedef __attribute__((ext_vector_type(4))) float f32x4;

__device__ __forceinline__ float b2f(unsigned short u) {
  union { unsigned u32; float f; } c; c.u32 = ((unsigned)u) << 16; return c.f;
}
__device__ __forceinline__ unsigned short f2b(float f) {
  union { float f; unsigned u; } c; c.f = f;
  unsigned u = c.u;
  return (unsigned short)((u + 0x7FFFu + ((u >> 16) & 1u)) >> 16);  // RNE
}

// ---------------- fp32 -> bf16 cast, 8 elems/thread ----------------
__global__ __launch_bounds__(256) void cast_f32_bf16(const float* __restrict__ in,
                                                     unsigned short* __restrict__ out,
                                                     int n8) {
  int i = blockIdx.x * 256 + threadIdx.x;
  if (i >= n8) return;
  const float4* p = (const float4*)in + (size_t)i * 2;
  float4 a = p[0], b = p[1];
  union { bf16x8 v; unsigned short s[8]; } o;
  o.s[0] = f2b(a.x); o.s[1] = f2b(a.y); o.s[2] = f2b(a.z); o.s[3] = f2b(a.w);
  o.s[4] = f2b(b.x); o.s[5] = f2b(b.y); o.s[6] = f2b(b.z); o.s[7] = f2b(b.w);
  ((bf16x8*)out)[i] = o.v;
}

// ---------------- bf16 GEMM, C = A * B^T (+bias) -------------------
// A: M x K row-major (bf16), B: N x K row-major (bf16).
// 128x128 tile, BK=32, 4 waves each 64x64 (4x4 of 16x16x32 mfma).
// m97 structure: global_load_lds width=16, 2 barriers per K-step.
#define GLDS16(g, l)                                                          \
  __builtin_amdgcn_global_load_lds((const __attribute__((address_space(1))) void*)(g), \
                                   (__attribute__((address_space(3))) void*)(l), 16, 0, 0)

template <typename OutT, bool BIAS>
__global__ __launch_bounds__(256) void gemm_bt(const unsigned short* __restrict__ A,
                                               const unsigned short* __restrict__ B,
                                               OutT* __restrict__ C,
                                               const float* __restrict__ bias,
                                               int M, int N, int K) {
  __shared__ unsigned short As[128 * 32];
  __shared__ unsigned short Bs[128 * 32];
  const int tid  = threadIdx.x;
  const int lane = tid & 63;
  const int wave = tid >> 6;
  const int tileM = blockIdx.y * 128;
  const int tileN = blockIdx.x * 128;

  const int m_off = (wave >> 1) * 64;  // wave grid 2x2, each wave 64x64
  const int n_off = (wave & 1) * 64;

  f32x4 acc[4][4] = {};

  // staging: 256 threads * 16B = 4KB per issue; tile is 8KB -> 2 issues each.
  const int srow = tid >> 2;       // 0..63
  const int scol = (tid & 3) * 8;  // element col
  const unsigned short* gA = A + (size_t)(tileM + srow) * K + scol;
  const unsigned short* gB = B + (size_t)(tileN + srow) * K + scol;
  unsigned short* lA = &As[tid * 8];
  unsigned short* lB = &Bs[tid * 8];

  const int lr = lane & 15;        // fragment row/col within 16
  const int lk = (lane >> 4) * 8;  // fragment k offset

  for (int k0 = 0; k0 < K; k0 += 32) {
    GLDS16(gA, lA);
    GLDS16(gA + (size_t)64 * K, lA + 2048);
    GLDS16(gB, lB);
    GLDS16(gB + (size_t)64 * K, lB + 2048);
    gA += 32; gB += 32;
    __syncthreads();  // drains vmcnt -> LDS tiles valid

    bf16x8 af[4], bfr[4];
#pragma unroll
    for (int m = 0; m < 4; ++m)
      af[m] = *(const bf16x8*)&As[(m_off + m * 16 + lr) * 32 + lk];
#pragma unroll
    for (int n = 0; n < 4; ++n)
      bfr[n] = *(const bf16x8*)&Bs[(n_off + n * 16 + lr) * 32 + lk];

#pragma unroll
    for (int m = 0; m < 4; ++m)
#pragma unroll
      for (int n = 0; n < 4; ++n)
        acc[m][n] = __builtin_amdgcn_mfma_f32_16x16x32_bf16(af[m], bfr[n], acc[m][n], 0, 0, 0);
    __syncthreads();  // all waves done reading before next stage overwrites
  }

  // C/D layout (m89-verified): col = lane&15, row = (lane>>4)*4 + j
  const int crow0 = (lane >> 4) * 4;
  const int ccol  = lane & 15;
#pragma unroll
  for (int n = 0; n < 4; ++n) {
    const int col = tileN + n_off + n * 16 + ccol;
    float bv = 0.f;
    if (BIAS) bv = bias[col];
#pragma unroll
    for (int m = 0; m < 4; ++m) {
#pragma unroll
      for (int j = 0; j < 4; ++j) {
        const int row = tileM + m_off + m * 16 + crow0 + j;
        float v = acc[m][n][j] + bv;
        if constexpr (sizeof(OutT) == 2)
          ((unsigned short*)C)[(size_t)row * N + col] = f2b(v);
        else
          ((float*)C)[(size_t)row * N + col] = v;
      }
    }
  }
}

// ---------------- per-token attention over heads --------------------
// att[h][g] = dot64(q[h],k[g])/8 ; softmax over g ; out[h][d] = sum_g p*v[g][d].
// One wave per token. lane = (h = lane>>2, s = lane&3); lane owns d-slice
// [s*16, s*16+16) of head h for q (regs), k, v (LDS, wave-private).
// K/V rows are 256B (bank-aligned) -> XOR-swizzle float4 granules by
// ((row&7)<<2) elems: writes spread across all 8 16B slots (balanced),
// reads are wave-uniform per g (broadcast, conflict-free).
__global__ __launch_bounds__(256) void attn_heads(const unsigned short* __restrict__ qkv,
                                                  unsigned short* __restrict__ attout) {
  __shared__ float kvs[4][2][16 * 64];
  const int wave = threadIdx.x >> 6;
  const int lane = threadIdx.x & 63;
  const size_t tok = (size_t)blockIdx.x * 4 + wave;
  const int h = lane >> 2;
  const int s = lane & 3;

  const unsigned short* base = qkv + tok * 3072 + h * 192 + s * 16;
  bf16x8 q0 = *(const bf16x8*)(base);
  bf16x8 q1 = *(const bf16x8*)(base + 8);
  bf16x8 k0 = *(const bf16x8*)(base + 64);
  bf16x8 k1 = *(const bf16x8*)(base + 72);
  bf16x8 v0 = *(const bf16x8*)(base + 128);
  bf16x8 v1 = *(const bf16x8*)(base + 136);

  float q[16], kr[16], vr[16];
#pragma unroll
  for (int j = 0; j < 8; ++j) {
    q[j]      = b2f((unsigned short)q0[j]);
    q[8 + j]  = b2f((unsigned short)q1[j]);
    kr[j]     = b2f((unsigned short)k0[j]);
    kr[8 + j] = b2f((unsigned short)k1[j]);
    vr[j]     = b2f((unsigned short)v0[j]);
    vr[8 + j] = b2f((unsigned short)v1[j]);
  }

  float* kb = kvs[wave][0];
  float* vb = kvs[wave][1];
  // write own head-row h, slice s (4 float4 chunks), swizzled
#pragma unroll
  for (int c = 0; c < 4; ++c) {
    const int off = h * 64 + (((s * 4 + c) * 4) ^ ((h & 7) << 2));
    *(float4*)&kb[off] = make_float4(kr[c * 4], kr[c * 4 + 1], kr[c * 4 + 2], kr[c * 4 + 3]);
    *(float4*)&vb[off] = make_float4(vr[c * 4], vr[c * 4 + 1], vr[c * 4 + 2], vr[c * 4 + 3]);
  }
  // wave-private LDS region: no __syncthreads needed (in-order DS pipe).

  // ---- QK^T: att[g] = (q[h] . k[g]) / 8, full row in every lane ----
  float att[16];
#pragma unroll
  for (int g = 0; g < 16; ++g) {
    float a = 0.f;
#pragma unroll
    for (int c = 0; c < 4; ++c) {
      const int off = g * 64 + (((s * 4 + c) * 4) ^ ((g & 7) << 2));
      float4 kf = *(const float4*)&kb[off];
      a += q[c * 4 + 0] * kf.x + q[c * 4 + 1] * kf.y +
           q[c * 4 + 2] * kf.z + q[c * 4 + 3] * kf.w;
    }
    a += __shfl_xor(a, 1);
    a += __shfl_xor(a, 2);
    att[g] = a * 0.125f;
  }

  // ---- softmax over g, fully in-lane ----
  float mx = att[0];
#pragma unroll
  for (int g = 1; g < 16; ++g) mx = fmaxf(mx, att[g]);
  float sum = 0.f;
#pragma unroll
  for (int g = 0; g < 16; ++g) { att[g] = __expf(att[g] - mx); sum += att[g]; }
  const float inv = 1.f / sum;

  // ---- PV: o[d-slice] = sum_g p[g] * v[g][d-slice] ----
  float o[16];
#pragma unroll
  for (int j = 0; j < 16; ++j) o[j] = 0.f;
#pragma unroll
  for (int g = 0; g < 16; ++g) {
    const float pg = att[g];
#pragma unroll
    for (int c = 0; c < 4; ++c) {
      const int off = g * 64 + (((s * 4 + c) * 4) ^ ((g & 7) << 2));
      float4 vf = *(const float4*)&vb[off];
      o[c * 4 + 0] += pg * vf.x;
      o[c * 4 + 1] += pg * vf.y;
      o[c * 4 + 2] += pg * vf.z;
      o[c * 4 + 3] += pg * vf.w;
    }
  }

  union { bf16x8 v[2]; unsigned short u[16]; } ob;
#pragma unroll
  for (int j = 0; j < 16; ++j) ob.u[j] = f2b(o[j] * inv);
  bf16x8* dst = (bf16x8*)&attout[tok * 1024 + h * 64 + s * 16];
  dst[0] = ob.v[0];
  dst[1] = ob.v[1];
}

// ---------------- launch ----------------
extern "C" void kernel_launch(void* const* d_in, const int* in_sizes, int n_in,
                              void* d_out, int out_size, void* d_ws, size_t ws_size,
                              hipStream_t stream) {
  const float* x    = (const float*)d_in[0];  // (4,4096,1024)
  const float* Wqkv = (const float*)d_in[1];  // (3072,1024)
  const float* Wout = (const float*)d_in[2];  // (1024,1024)
  const float* bout = (const float*)d_in[3];  // (1024,)
  float* out = (float*)d_out;                 // (4,4096,1024) fp32

  char* ws = (char*)d_ws;
  unsigned short* xb     = (unsigned short*)(ws);                     // 33.5 MB
  unsigned short* wqkvb  = (unsigned short*)(ws + 33554432);          // 6.3 MB
  unsigned short* woutb  = (unsigned short*)(ws + 39845888);          // 2.1 MB
  unsigned short* qkv    = (unsigned short*)(ws + 41943040);          // 100.7 MB
  unsigned short* attout = (unsigned short*)(ws + 142606336);         // 33.5 MB

  cast_f32_bf16<<<8192, 256, 0, stream>>>(x, xb, 2097152);
  cast_f32_bf16<<<1536, 256, 0, stream>>>(Wqkv, wqkvb, 393216);
  cast_f32_bf16<<<512, 256, 0, stream>>>(Wout, woutb, 131072);

  // qkv = x @ Wqkv^T : M=16384 N=3072 K=1024
  gemm_bt<unsigned short, false><<<dim3(24, 128), 256, 0, stream>>>(
      xb, wqkvb, qkv, nullptr, 16384, 3072, 1024);

  attn_heads<<<4096, 256, 0, stream>>>(qkv, attout);

  // out = attout @ Wout^T + bout : M=16384 N=1024 K=1024
  gemm_bt<float, true><<<dim3(8, 128), 256, 0, stream>>>(
      attout, woutb, out, bout, 16384, 1024, 1024);
}

// Round 3
// 346.166 us; speedup vs baseline: 1.1397x; 1.0642x over previous
//
#include <hip/hip_runtime.h>
#include <hip/hip_bf16.h>
#include <stdint.h>

typedef __attribute__((ext_vector_type(8))) short bf16x8;
typedef __attribute__((ext_vector_type(4))) float f32x4;
typedef unsigned short ushort_t;

__device__ __forceinline__ float b2f(unsigned short u) {
  union { unsigned u32; float f; } c; c.u32 = ((unsigned)u) << 16; return c.f;
}
__device__ __forceinline__ unsigned short f2b(float f) {
  union { float f; unsigned u; } c; c.f = f;
  unsigned u = c.u;
  return (unsigned short)((u + 0x7FFFu + ((u >> 16) & 1u)) >> 16);  // RNE
}

// ---------------- fp32 -> bf16 cast, 8 elems/thread ----------------
__global__ __launch_bounds__(256) void cast_f32_bf16(const float* __restrict__ in,
                                                     unsigned short* __restrict__ out,
                                                     int n8) {
  int i = blockIdx.x * 256 + threadIdx.x;
  if (i >= n8) return;
  const float4* p = (const float4*)in + (size_t)i * 2;
  float4 a = p[0], b = p[1];
  union { bf16x8 v; unsigned short s[8]; } o;
  o.s[0] = f2b(a.x); o.s[1] = f2b(a.y); o.s[2] = f2b(a.z); o.s[3] = f2b(a.w);
  o.s[4] = f2b(b.x); o.s[5] = f2b(b.y); o.s[6] = f2b(b.z); o.s[7] = f2b(b.w);
  ((bf16x8*)out)[i] = o.v;
}

// =====================================================================
// 256x256 8-phase bf16 GEMM, C = A * B^T (+bias).  BK=64, 8 waves.
// Wave grid 2(M)x4(N); wave output = two 64-row strips (one per A-half)
// x 64 cols.  LDS 128 KiB: 2 dbuf x (A 32KB + B 32KB).
// Swizzle: LDS slot(row, s) holds global granule s ^ (row&7) (16B granules)
// -- applied on the global SOURCE address (linear global_load_lds dest)
// and identically on the ds_read side (rule #21).
// Stage stream per K-tile t: ph0->(t+1).B0, ph1->(t+1).B1, ph2->(t+1).A1,
// ph3->(t+2).A0 ; vmcnt(4) at ph0/ph3 ends. Race-freedom: every stage
// target's last reader phase is barrier-separated from the stage issue.
// =====================================================================
#define GLDS16(g, l)                                                          \
  __builtin_amdgcn_global_load_lds((const __attribute__((address_space(1))) void*)(g), \
                                   (__attribute__((address_space(3))) void*)(l), 16, 0, 0)

#define BAR1()                                             \
  __builtin_amdgcn_s_barrier();                            \
  asm volatile("s_waitcnt lgkmcnt(0)" ::: "memory");       \
  __builtin_amdgcn_sched_barrier(0)

#define BAR2()                                             \
  __builtin_amdgcn_sched_barrier(0);                       \
  __builtin_amdgcn_s_barrier();                            \
  asm volatile("" ::: "memory")

#define VM4() asm volatile("s_waitcnt vmcnt(4)" ::: "memory")

template <typename OutT, bool BIAS>
__global__ __launch_bounds__(512, 2) void gemm8p(const unsigned short* __restrict__ A,
                                                 const unsigned short* __restrict__ B,
                                                 OutT* __restrict__ C,
                                                 const float* __restrict__ bias,
                                                 int M, int N, int K) {
  __shared__ ushort_t smA[2 * 16384];  // [p][row 0..255][granule slot 0..7][8]
  __shared__ ushort_t smB[2 * 16384];

  const int tid  = threadIdx.x;
  const int lane = tid & 63;
  const int wave = tid >> 6;
  const int wm = wave >> 2;   // 0..1
  const int wn = wave & 3;    // 0..3
  const int tileM = blockIdx.y * 256;
  const int tileN = blockIdx.x * 256;
  const int NT = K >> 6;

  // ---- staging addresses (source-side swizzle) ----
  const int srow = tid >> 3;                       // 0..63
  const int sg   = (tid & 7) ^ (srow & 7);         // swizzled source granule
  const unsigned short* Abase = A + (size_t)(tileM + srow) * K + sg * 8;
  const unsigned short* Bbase = B + (size_t)(tileN + srow) * K + sg * 8;

#define STAGE_A(h, tt, pp) {                                                   \
    const unsigned short* s_ = Abase + (size_t)(h) * 128 * K + (size_t)(tt) * 64; \
    GLDS16(s_, &smA[(pp) * 16384 + (h) * 8192 + tid * 8]);                     \
    GLDS16(s_ + (size_t)64 * K, &smA[(pp) * 16384 + (h) * 8192 + 4096 + tid * 8]); }
#define STAGE_B(h, tt, pp) {                                                   \
    const unsigned short* s_ = Bbase + (size_t)(h) * 128 * K + (size_t)(tt) * 64; \
    GLDS16(s_, &smB[(pp) * 16384 + (h) * 8192 + tid * 8]);                     \
    GLDS16(s_ + (size_t)64 * K, &smB[(pp) * 16384 + (h) * 8192 + 4096 + tid * 8]); }

  // ---- read-side fragment addressing ----
  const int lr  = lane & 15;            // fragment row within 16
  const int kg  = lane >> 4;            // k-granule group 0..3
  const int gx0 = kg ^ (lr & 7);        // swizzled granule, ks=0
  const int gx1 = gx0 ^ 4;              // ks=1
  // rows are multiples of 8 plus lr, so (row&7)==(lr&7): fold into gx.
#define LDSA(pp, row, gx) (*(const bf16x8*)&smA[(pp) * 16384 + (row) * 64 + ((gx) << 3)])
#define LDSB(pp, row, gx) (*(const bf16x8*)&smB[(pp) * 16384 + (row) * 64 + ((gx) << 3)])

  f32x4 acc[8][4] = {};
  bf16x8 af[4], bf[4];

#define MFMA16(mh)                                                   \
  __builtin_amdgcn_s_setprio(1);                                     \
  _Pragma("unroll") for (int m = 0; m < 4; ++m)                      \
    _Pragma("unroll") for (int n = 0; n < 4; ++n)                    \
      acc[(mh) * 4 + m][n] =                                         \
          __builtin_amdgcn_mfma_f32_16x16x32_bf16(af[m], bf[n], acc[(mh) * 4 + m][n], 0, 0, 0); \
  __builtin_amdgcn_s_setprio(0)

  // ---- prologue: t0 all 4 halves + t1.A0 ; vmcnt(2) leaves t1.A0 in flight
  STAGE_A(0, 0, 0); STAGE_A(1, 0, 0); STAGE_B(0, 0, 0); STAGE_B(1, 0, 0);
  STAGE_A(0, 1, 1);
  asm volatile("s_waitcnt vmcnt(2)" ::: "memory");
  __builtin_amdgcn_s_barrier();
  asm volatile("" ::: "memory");

  const int arow0 = wm * 64 + lr;        // A row base (mh adds +128)
  const int brow0 = wn * 64 + lr;        // B row base

  for (int t = 0; t < NT; ++t) {
    const int p  = t & 1;
    const int pn = p ^ 1;
    const bool s1 = (t + 1) < NT;
    const bool s2 = (t + 2) < NT;

    // ---- ph0: ks0 mh0 ; stage (t+1).B0 ; vmcnt(4)
#pragma unroll
    for (int n = 0; n < 4; ++n) bf[n] = LDSB(p, brow0 + n * 16, gx0);
#pragma unroll
    for (int m = 0; m < 4; ++m) af[m] = LDSA(p, arow0 + m * 16, gx0);
    if (s1) STAGE_B(0, t + 1, pn);
    BAR1();
    MFMA16(0);
    VM4();
    BAR2();

    // ---- ph1: ks0 mh1 ; stage (t+1).B1  (bf reused)
#pragma unroll
    for (int m = 0; m < 4; ++m) af[m] = LDSA(p, 128 + arow0 + m * 16, gx0);
    if (s1) STAGE_B(1, t + 1, pn);
    BAR1();
    MFMA16(1);
    BAR2();

    // ---- ph2: ks1 mh0 ; stage (t+1).A1
#pragma unroll
    for (int n = 0; n < 4; ++n) bf[n] = LDSB(p, brow0 + n * 16, gx1);
#pragma unroll
    for (int m = 0; m < 4; ++m) af[m] = LDSA(p, arow0 + m * 16, gx1);
    if (s1) STAGE_A(1, t + 1, pn);
    BAR1();
    MFMA16(0);
    BAR2();

    // ---- ph3: ks1 mh1 ; stage (t+2).A0 ; vmcnt(4)
#pragma unroll
    for (int m = 0; m < 4; ++m) af[m] = LDSA(p, 128 + arow0 + m * 16, gx1);
    if (s2) STAGE_A(0, t + 2, p);
    BAR1();
    MFMA16(1);
    VM4();
    BAR2();
  }

  // ---- epilogue: C/D layout col=lane&15, row=(lane>>4)*4+j (m89-verified)
  const int crow0 = (lane >> 4) * 4;
  const int ccol  = lane & 15;
#pragma unroll
  for (int n = 0; n < 4; ++n) {
    const int col = tileN + wn * 64 + n * 16 + ccol;
    float bv = 0.f;
    if (BIAS) bv = bias[col];
#pragma unroll
    for (int m = 0; m < 8; ++m) {
      const int row = tileM + (m >> 2) * 128 + wm * 64 + (m & 3) * 16 + crow0;
#pragma unroll
      for (int j = 0; j < 4; ++j) {
        float v = acc[m][n][j] + bv;
        if constexpr (sizeof(OutT) == 2)
          ((unsigned short*)C)[(size_t)(row + j) * N + col] = f2b(v);
        else
          ((float*)C)[(size_t)(row + j) * N + col] = v;
      }
    }
  }
}

// ---------------- per-token attention over heads --------------------
__global__ __launch_bounds__(256) void attn_heads(const unsigned short* __restrict__ qkv,
                                                  unsigned short* __restrict__ attout) {
  __shared__ float kvs[4][2][16 * 64];
  const int wave = threadIdx.x >> 6;
  const int lane = threadIdx.x & 63;
  const size_t tok = (size_t)blockIdx.x * 4 + wave;
  const int h = lane >> 2;
  const int s = lane & 3;

  const unsigned short* base = qkv + tok * 3072 + h * 192 + s * 16;
  bf16x8 q0 = *(const bf16x8*)(base);
  bf16x8 q1 = *(const bf16x8*)(base + 8);
  bf16x8 k0 = *(const bf16x8*)(base + 64);
  bf16x8 k1 = *(const bf16x8*)(base + 72);
  bf16x8 v0 = *(const bf16x8*)(base + 128);
  bf16x8 v1 = *(const bf16x8*)(base + 136);

  float q[16], kr[16], vr[16];
#pragma unroll
  for (int j = 0; j < 8; ++j) {
    q[j]      = b2f((unsigned short)q0[j]);
    q[8 + j]  = b2f((unsigned short)q1[j]);
    kr[j]     = b2f((unsigned short)k0[j]);
    kr[8 + j] = b2f((unsigned short)k1[j]);
    vr[j]     = b2f((unsigned short)v0[j]);
    vr[8 + j] = b2f((unsigned short)v1[j]);
  }

  float* kb = kvs[wave][0];
  float* vb = kvs[wave][1];
#pragma unroll
  for (int c = 0; c < 4; ++c) {
    const int off = h * 64 + (((s * 4 + c) * 4) ^ ((h & 7) << 2));
    *(float4*)&kb[off] = make_float4(kr[c * 4], kr[c * 4 + 1], kr[c * 4 + 2], kr[c * 4 + 3]);
    *(float4*)&vb[off] = make_float4(vr[c * 4], vr[c * 4 + 1], vr[c * 4 + 2], vr[c * 4 + 3]);
  }

  float att[16];
#pragma unroll
  for (int g = 0; g < 16; ++g) {
    float a = 0.f;
#pragma unroll
    for (int c = 0; c < 4; ++c) {
      const int off = g * 64 + (((s * 4 + c) * 4) ^ ((g & 7) << 2));
      float4 kf = *(const float4*)&kb[off];
      a += q[c * 4 + 0] * kf.x + q[c * 4 + 1] * kf.y +
           q[c * 4 + 2] * kf.z + q[c * 4 + 3] * kf.w;
    }
    a += __shfl_xor(a, 1);
    a += __shfl_xor(a, 2);
    att[g] = a * 0.125f;
  }

  float mx = att[0];
#pragma unroll
  for (int g = 1; g < 16; ++g) mx = fmaxf(mx, att[g]);
  float sum = 0.f;
#pragma unroll
  for (int g = 0; g < 16; ++g) { att[g] = __expf(att[g] - mx); sum += att[g]; }
  const float inv = 1.f / sum;

  float o[16];
#pragma unroll
  for (int j = 0; j < 16; ++j) o[j] = 0.f;
#pragma unroll
  for (int g = 0; g < 16; ++g) {
    const float pg = att[g];
#pragma unroll
    for (int c = 0; c < 4; ++c) {
      const int off = g * 64 + (((s * 4 + c) * 4) ^ ((g & 7) << 2));
      float4 vf = *(const float4*)&vb[off];
      o[c * 4 + 0] += pg * vf.x;
      o[c * 4 + 1] += pg * vf.y;
      o[c * 4 + 2] += pg * vf.z;
      o[c * 4 + 3] += pg * vf.w;
    }
  }

  union { bf16x8 v[2]; unsigned short u[16]; } ob;
#pragma unroll
  for (int j = 0; j < 16; ++j) ob.u[j] = f2b(o[j] * inv);
  bf16x8* dst = (bf16x8*)&attout[tok * 1024 + h * 64 + s * 16];
  dst[0] = ob.v[0];
  dst[1] = ob.v[1];
}

// ---------------- launch ----------------
extern "C" void kernel_launch(void* const* d_in, const int* in_sizes, int n_in,
                              void* d_out, int out_size, void* d_ws, size_t ws_size,
                              hipStream_t stream) {
  const float* x    = (const float*)d_in[0];  // (4,4096,1024)
  const float* Wqkv = (const float*)d_in[1];  // (3072,1024)
  const float* Wout = (const float*)d_in[2];  // (1024,1024)
  const float* bout = (const float*)d_in[3];  // (1024,)
  float* out = (float*)d_out;                 // (4,4096,1024) fp32

  char* ws = (char*)d_ws;
  unsigned short* xb     = (unsigned short*)(ws);                     // 33.5 MB
  unsigned short* wqkvb  = (unsigned short*)(ws + 33554432);          // 6.3 MB
  unsigned short* woutb  = (unsigned short*)(ws + 39845888);          // 2.1 MB
  unsigned short* qkv    = (unsigned short*)(ws + 41943040);          // 100.7 MB
  unsigned short* attout = (unsigned short*)(ws + 142606336);         // 33.5 MB

  cast_f32_bf16<<<8192, 256, 0, stream>>>(x, xb, 2097152);
  cast_f32_bf16<<<1536, 256, 0, stream>>>(Wqkv, wqkvb, 393216);
  cast_f32_bf16<<<512, 256, 0, stream>>>(Wout, woutb, 131072);

  // qkv = x @ Wqkv^T : M=16384 N=3072 K=1024
  gemm8p<unsigned short, false><<<dim3(12, 64), 512, 0, stream>>>(
      xb, wqkvb, qkv, nullptr, 16384, 3072, 1024);

  attn_heads<<<4096, 256, 0, stream>>>(qkv, attout);

  // out = attout @ Wout^T + bout : M=16384 N=1024 K=1024
  gemm8p<float, true><<<dim3(4, 64), 512, 0, stream>>>(
      attout, woutb, out, bout, 16384, 1024, 1024);
}

// Round 5
// 295.862 us; speedup vs baseline: 1.3335x; 1.1700x over previous
//
#include <hip/hip_runtime.h>
#include <hip/hip_bf16.h>
#include <stdint.h>

typedef __attribute__((ext_vector_type(8))) short bf16x8;
typedef __attribute__((ext_vector_type(4))) short bf16x4;
typedef __attribute__((ext_vector_type(4))) float f32x4;
typedef unsigned short ushort_t;

__device__ __forceinline__ float b2f(unsigned short u) {
  union { unsigned u32; float f; } c; c.u32 = ((unsigned)u) << 16; return c.f;
}
__device__ __forceinline__ unsigned short f2b(float f) {
  union { float f; unsigned u; } c; c.f = f;
  unsigned u = c.u;
  return (unsigned short)((u + 0x7FFFu + ((u >> 16) & 1u)) >> 16);  // RNE
}

// ---------------- fp32 -> bf16 cast, 8 elems/thread ----------------
__global__ __launch_bounds__(256) void cast_f32_bf16(const float* __restrict__ in,
                                                     unsigned short* __restrict__ out,
                                                     int n8) {
  int i = blockIdx.x * 256 + threadIdx.x;
  if (i >= n8) return;
  const float4* p = (const float4*)in + (size_t)i * 2;
  float4 a = p[0], b = p[1];
  union { bf16x8 v; unsigned short s[8]; } o;
  o.s[0] = f2b(a.x); o.s[1] = f2b(a.y); o.s[2] = f2b(a.z); o.s[3] = f2b(a.w);
  o.s[4] = f2b(b.x); o.s[5] = f2b(b.y); o.s[6] = f2b(b.z); o.s[7] = f2b(b.w);
  ((bf16x8*)out)[i] = o.v;
}

// =====================================================================
// 256x256 8-phase bf16 GEMM, C = A * B^T (+bias).  BK=64, 8 waves.
// (round-3 notes; this round: coalesced epilogue + XCD swizzle)
// =====================================================================
#define GLDS16(g, l)                                                          \
  __builtin_amdgcn_global_load_lds((const __attribute__((address_space(1))) void*)(g), \
                                   (__attribute__((address_space(3))) void*)(l), 16, 0, 0)

#define BAR1()                                             \
  __builtin_amdgcn_s_barrier();                            \
  asm volatile("s_waitcnt lgkmcnt(0)" ::: "memory");       \
  __builtin_amdgcn_sched_barrier(0)

#define BAR2()                                             \
  __builtin_amdgcn_sched_barrier(0);                       \
  __builtin_amdgcn_s_barrier();                            \
  asm volatile("" ::: "memory")

#define VM4() asm volatile("s_waitcnt vmcnt(4)" ::: "memory")

template <typename OutT, bool BIAS>
__global__ __launch_bounds__(512, 2) void gemm8p(const unsigned short* __restrict__ A,
                                                 const unsigned short* __restrict__ B,
                                                 OutT* __restrict__ C,
                                                 const float* __restrict__ bias,
                                                 int M, int N, int K) {
  __shared__ ushort_t smA[2 * 16384];
  __shared__ ushort_t smB[2 * 16384];

  const int tid  = threadIdx.x;
  const int lane = tid & 63;
  const int wave = tid >> 6;
  const int wm = wave >> 2;   // 0..1
  const int wn = wave & 3;    // 0..3

  // T1: bijective XCD swizzle (nwg % 8 == 0 for both gemms)
  const int nwg = gridDim.x * gridDim.y;
  const int bid = blockIdx.y * gridDim.x + blockIdx.x;
  const int swz = (bid & 7) * (nwg >> 3) + (bid >> 3);
  const int tileM = (swz / gridDim.x) * 256;
  const int tileN = (swz % gridDim.x) * 256;
  const int NT = K >> 6;

  const int srow = tid >> 3;                       // 0..63
  const int sg   = (tid & 7) ^ (srow & 7);         // swizzled source granule
  const unsigned short* Abase = A + (size_t)(tileM + srow) * K + sg * 8;
  const unsigned short* Bbase = B + (size_t)(tileN + srow) * K + sg * 8;

#define STAGE_A(h, tt, pp) {                                                   \
    const unsigned short* s_ = Abase + (size_t)(h) * 128 * K + (size_t)(tt) * 64; \
    GLDS16(s_, &smA[(pp) * 16384 + (h) * 8192 + tid * 8]);                     \
    GLDS16(s_ + (size_t)64 * K, &smA[(pp) * 16384 + (h) * 8192 + 4096 + tid * 8]); }
#define STAGE_B(h, tt, pp) {                                                   \
    const unsigned short* s_ = Bbase + (size_t)(h) * 128 * K + (size_t)(tt) * 64; \
    GLDS16(s_, &smB[(pp) * 16384 + (h) * 8192 + tid * 8]);                     \
    GLDS16(s_ + (size_t)64 * K, &smB[(pp) * 16384 + (h) * 8192 + 4096 + tid * 8]); }

  const int lr  = lane & 15;
  const int kg  = lane >> 4;
  const int gx0 = kg ^ (lr & 7);
  const int gx1 = gx0 ^ 4;
#define LDSA(pp, row, gx) (*(const bf16x8*)&smA[(pp) * 16384 + (row) * 64 + ((gx) << 3)])
#define LDSB(pp, row, gx) (*(const bf16x8*)&smB[(pp) * 16384 + (row) * 64 + ((gx) << 3)])

  f32x4 acc[8][4] = {};
  bf16x8 af[4], bf[4];

#define MFMA16(mh)                                                   \
  __builtin_amdgcn_s_setprio(1);                                     \
  _Pragma("unroll") for (int m = 0; m < 4; ++m)                      \
    _Pragma("unroll") for (int n = 0; n < 4; ++n)                    \
      acc[(mh) * 4 + m][n] =                                         \
          __builtin_amdgcn_mfma_f32_16x16x32_bf16(af[m], bf[n], acc[(mh) * 4 + m][n], 0, 0, 0); \
  __builtin_amdgcn_s_setprio(0)

  STAGE_A(0, 0, 0); STAGE_A(1, 0, 0); STAGE_B(0, 0, 0); STAGE_B(1, 0, 0);
  STAGE_A(0, 1, 1);
  asm volatile("s_waitcnt vmcnt(2)" ::: "memory");
  __builtin_amdgcn_s_barrier();
  asm volatile("" ::: "memory");

  const int arow0 = wm * 64 + lr;
  const int brow0 = wn * 64 + lr;

  for (int t = 0; t < NT; ++t) {
    const int p  = t & 1;
    const int pn = p ^ 1;
    const bool s1 = (t + 1) < NT;
    const bool s2 = (t + 2) < NT;

#pragma unroll
    for (int n = 0; n < 4; ++n) bf[n] = LDSB(p, brow0 + n * 16, gx0);
#pragma unroll
    for (int m = 0; m < 4; ++m) af[m] = LDSA(p, arow0 + m * 16, gx0);
    if (s1) STAGE_B(0, t + 1, pn);
    BAR1();
    MFMA16(0);
    VM4();
    BAR2();

#pragma unroll
    for (int m = 0; m < 4; ++m) af[m] = LDSA(p, 128 + arow0 + m * 16, gx0);
    if (s1) STAGE_B(1, t + 1, pn);
    BAR1();
    MFMA16(1);
    BAR2();

#pragma unroll
    for (int n = 0; n < 4; ++n) bf[n] = LDSB(p, brow0 + n * 16, gx1);
#pragma unroll
    for (int m = 0; m < 4; ++m) af[m] = LDSA(p, arow0 + m * 16, gx1);
    if (s1) STAGE_A(1, t + 1, pn);
    BAR1();
    MFMA16(0);
    BAR2();

#pragma unroll
    for (int m = 0; m < 4; ++m) af[m] = LDSA(p, 128 + arow0 + m * 16, gx1);
    if (s2) STAGE_A(0, t + 2, p);
    BAR1();
    MFMA16(1);
    VM4();
    BAR2();
  }

  // ---- epilogue: n INNERMOST so each wave's 4 stores cover a contiguous
  // 128B span back-to-back (full-line writeback, no RFO).
  const int crow0 = (lane >> 4) * 4;
  const int ccol  = lane & 15;
  float bv[4];
#pragma unroll
  for (int n = 0; n < 4; ++n)
    bv[n] = BIAS ? bias[tileN + wn * 64 + n * 16 + ccol] : 0.f;
#pragma unroll
  for (int m = 0; m < 8; ++m) {
#pragma unroll
    for (int j = 0; j < 4; ++j) {
      const int row = tileM + (m >> 2) * 128 + wm * 64 + (m & 3) * 16 + crow0 + j;
#pragma unroll
      for (int n = 0; n < 4; ++n) {
        const int col = tileN + wn * 64 + n * 16 + ccol;
        float v = acc[m][n][j] + bv[n];
        if constexpr (sizeof(OutT) == 2)
          ((unsigned short*)C)[(size_t)row * N + col] = f2b(v);
        else
          ((float*)C)[(size_t)row * N + col] = v;
      }
    }
  }
}

// ---------------- per-token attention over heads, MFMA version ------
// Swapped QK^T: attT = mfma(K,Q) -> attT[g=4*hi+jj][h=lo].  Softmax over
// g = 4 local slots + shfl_xor(16,32).  P lands EXACTLY in the A-layout
// (row=lo, k=4*hi+jj) for the 16x16x16 PV mfma -- zero data movement.
static __device__ __forceinline__ f32x4 mfma_pv(bf16x4 a, bf16x4 b, f32x4 c) {
#if __has_builtin(__builtin_amdgcn_mfma_f32_16x16x16_bf16)
  return __builtin_amdgcn_mfma_f32_16x16x16_bf16(a, b, c, 0, 0, 0);
#elif __has_builtin(__builtin_amdgcn_mfma_f32_16x16x16bf16_1k)
  return __builtin_amdgcn_mfma_f32_16x16x16bf16_1k(a, b, c, 0, 0, 0);
#else
  f32x4 d;
  asm volatile("v_mfma_f32_16x16x16_bf16 %0, %1, %2, %3"
               : "=&v"(d) : "v"(a), "v"(b), "v"(c));
  return d;
#endif
}

__global__ __launch_bounds__(256) void attn_mfma(const unsigned short* __restrict__ qkv,
                                                 unsigned short* __restrict__ attout) {
  const int wave = threadIdx.x >> 6;
  const int lane = threadIdx.x & 63;
  const int lo = lane & 15;
  const int hi = lane >> 4;
  const size_t tok = (size_t)blockIdx.x * 4 + wave;
  const unsigned short* base = qkv + tok * 3072;

  // QK^T (swapped): A = K rows (g=lo), B = Q rows (h=lo); k = d.
  const unsigned short* krow = base + lo * 192 + 64 + hi * 8;
  const unsigned short* qrow = base + lo * 192 + hi * 8;
  bf16x8 ka0 = *(const bf16x8*)(krow);
  bf16x8 ka1 = *(const bf16x8*)(krow + 32);
  bf16x8 qb0 = *(const bf16x8*)(qrow);
  bf16x8 qb1 = *(const bf16x8*)(qrow + 32);

  f32x4 att = {};
  att = __builtin_amdgcn_mfma_f32_16x16x32_bf16(ka0, qb0, att, 0, 0, 0);
  att = __builtin_amdgcn_mfma_f32_16x16x32_bf16(ka1, qb1, att, 0, 0, 0);
  // lane holds attT[g = 4*hi + jj][h = lo], jj = 0..3

  float s0 = att[0] * 0.125f, s1 = att[1] * 0.125f;
  float s2 = att[2] * 0.125f, s3 = att[3] * 0.125f;
  float mx = fmaxf(fmaxf(s0, s1), fmaxf(s2, s3));
  mx = fmaxf(mx, __shfl_xor(mx, 16));
  mx = fmaxf(mx, __shfl_xor(mx, 32));
  float e0 = __expf(s0 - mx), e1 = __expf(s1 - mx);
  float e2 = __expf(s2 - mx), e3 = __expf(s3 - mx);
  float sum = e0 + e1 + e2 + e3;
  sum += __shfl_xor(sum, 16);
  sum += __shfl_xor(sum, 32);
  const float inv = 1.f / sum;

  union { bf16x4 v; unsigned short u[4]; } pa;
  pa.u[0] = f2b(e0 * inv); pa.u[1] = f2b(e1 * inv);
  pa.u[2] = f2b(e2 * inv); pa.u[3] = f2b(e3 * inv);

  // PV: out[h, d] = sum_g P[h,g] V[g,d]; d in 4 chunks of 16.
  // B-frag chunk c: B[col = d_loc = lo][k = g = 4*hi+j] = V[4*hi+j][16c+lo]
  f32x4 o[4];
#pragma unroll
  for (int c = 0; c < 4; ++c) {
    union { bf16x4 v; unsigned short u[4]; } vb;
#pragma unroll
    for (int j = 0; j < 4; ++j)
      vb.u[j] = base[(4 * hi + j) * 192 + 128 + c * 16 + lo];
    f32x4 z = {};
    o[c] = mfma_pv(pa.v, vb.v, z);
  }

  // store: C[row = h = 4*hi+jj][col = d_loc = lo]; c inner -> 128B spans
  unsigned short* dst = attout + tok * 1024;
#pragma unroll
  for (int jj = 0; jj < 4; ++jj) {
#pragma unroll
    for (int c = 0; c < 4; ++c)
      dst[(4 * hi + jj) * 64 + c * 16 + lo] = f2b(o[c][jj]);
  }
}

// ---------------- launch ----------------
extern "C" void kernel_launch(void* const* d_in, const int* in_sizes, int n_in,
                              void* d_out, int out_size, void* d_ws, size_t ws_size,
                              hipStream_t stream) {
  const float* x    = (const float*)d_in[0];  // (4,4096,1024)
  const float* Wqkv = (const float*)d_in[1];  // (3072,1024)
  const float* Wout = (const float*)d_in[2];  // (1024,1024)
  const float* bout = (const float*)d_in[3];  // (1024,)
  float* out = (float*)d_out;                 // (4,4096,1024) fp32

  char* ws = (char*)d_ws;
  unsigned short* xb     = (unsigned short*)(ws);                     // 33.5 MB
  unsigned short* wqkvb  = (unsigned short*)(ws + 33554432);          // 6.3 MB
  unsigned short* woutb  = (unsigned short*)(ws + 39845888);          // 2.1 MB
  unsigned short* qkv    = (unsigned short*)(ws + 41943040);          // 100.7 MB
  unsigned short* attout = (unsigned short*)(ws + 142606336);         // 33.5 MB

  cast_f32_bf16<<<8192, 256, 0, stream>>>(x, xb, 2097152);
  cast_f32_bf16<<<1536, 256, 0, stream>>>(Wqkv, wqkvb, 393216);
  cast_f32_bf16<<<512, 256, 0, stream>>>(Wout, woutb, 131072);

  // qkv = x @ Wqkv^T : M=16384 N=3072 K=1024
  gemm8p<unsigned short, false><<<dim3(12, 64), 512, 0, stream>>>(
      xb, wqkvb, qkv, nullptr, 16384, 3072, 1024);

  attn_mfma<<<4096, 256, 0, stream>>>(qkv, attout);

  // out = attout @ Wout^T + bout : M=16384 N=1024 K=1024
  gemm8p<float, true><<<dim3(4, 64), 512, 0, stream>>>(
      attout, woutb, out, bout, 16384, 1024, 1024);
}